// Round 12
// baseline (118.671 us; speedup 1.0000x reference)
//
#include <hip/hip_runtime.h>
#include <math.h>

namespace {
constexpr int T    = 4096;
constexpr int C    = 64;
constexpr int NCH  = 4;
constexpr int TDAF = 50;
constexpr double LEAK = 0.9;
constexpr int CHUNK = 128;   // outputs per scan chunk (back to R10 best config)
constexpr int WARM  = 384;   // speculative warmup steps (0.9^384 ~ 2.6e-18)
}

// ============================ Phase 1: proj (v4) ===========================
// R7/R8-verified. Depth-3 load pipeline; 256 thr = 32 rows x 8 lanes; lane
// owns 8 fixed columns. grid = (B/4)*(T/64). UNCHANGED from R10.
__global__ __launch_bounds__(256, 2)
void lif_proj3(const float* __restrict__ x,    // [B,T,C]
               const float* __restrict__ Wsp,  // [NCH,C]
               const float* __restrict__ lat,  // [NCH,NCH]
               double* __restrict__ proj,      // [T][B*NCH] f64
               int B)
{
  const int tid = threadIdx.x;
  const int nb  = B >> 2;
  const int b0  = (blockIdx.x % nb) << 2;   // 4 b's
  const int t00 = (blockIdx.x / nb) << 6;   // 64 t's
  const int stride = B * NCH;

  const int c8 = tid & 7;                   // column octet 0..7
  const int rr = tid >> 3;                  // 0..31
  const int bl = rr & 3;                    // b_local
  const int tl = rr >> 2;                   // 0..7

  double wA[4][4], wB[4][4];                // [j][n], fully static
  #pragma unroll
  for (int j = 0; j < 4; ++j) {
    const int cA = c8 * 4 + j, cB = 32 + c8 * 4 + j;
    #pragma unroll
    for (int n = 0; n < 4; ++n) {
      double sA = 0.0, sB = 0.0;
      #pragma unroll
      for (int m = 0; m < 4; ++m) {
        sA += (double)Wsp[m * C + cA] * (double)lat[m * NCH + n];
        sB += (double)Wsp[m * C + cB] * (double)lat[m * NCH + n];
      }
      wA[j][n] = sA;
      wB[j][n] = sB;
    }
  }

  const float4* gx = reinterpret_cast<const float4*>(x);
  const size_t rowbase = (size_t)(b0 + bl) * T;

  float4 va0, vb0, va1, vb1, va2, vb2;      // named triple-buffer regs

#define LD(IT, VA, VB)                                              \
  {                                                                 \
    const size_t r16 = (rowbase + (size_t)(t00 + (IT) * 8 + tl)) * 16; \
    VA = gx[r16 + c8];                                              \
    VB = gx[r16 + 8 + c8];                                          \
  }

#define CS(IT, VA, VB)                                              \
  {                                                                 \
    double p0 = 0.0, p1 = 0.0, p2 = 0.0, p3 = 0.0;                  \
    p0 = fma((double)VA.x, wA[0][0], p0);                           \
    p1 = fma((double)VA.x, wA[0][1], p1);                           \
    p2 = fma((double)VA.x, wA[0][2], p2);                           \
    p3 = fma((double)VA.x, wA[0][3], p3);                           \
    p0 = fma((double)VA.y, wA[1][0], p0);                           \
    p1 = fma((double)VA.y, wA[1][1], p1);                           \
    p2 = fma((double)VA.y, wA[1][2], p2);                           \
    p3 = fma((double)VA.y, wA[1][3], p3);                           \
    p0 = fma((double)VA.z, wA[2][0], p0);                           \
    p1 = fma((double)VA.z, wA[2][1], p1);                           \
    p2 = fma((double)VA.z, wA[2][2], p2);                           \
    p3 = fma((double)VA.z, wA[2][3], p3);                           \
    p0 = fma((double)VA.w, wA[3][0], p0);                           \
    p1 = fma((double)VA.w, wA[3][1], p1);                           \
    p2 = fma((double)VA.w, wA[3][2], p2);                           \
    p3 = fma((double)VA.w, wA[3][3], p3);                           \
    p0 = fma((double)VB.x, wB[0][0], p0);                           \
    p1 = fma((double)VB.x, wB[0][1], p1);                           \
    p2 = fma((double)VB.x, wB[0][2], p2);                           \
    p3 = fma((double)VB.x, wB[0][3], p3);                           \
    p0 = fma((double)VB.y, wB[1][0], p0);                           \
    p1 = fma((double)VB.y, wB[1][1], p1);                           \
    p2 = fma((double)VB.y, wB[1][2], p2);                           \
    p3 = fma((double)VB.y, wB[1][3], p3);                           \
    p0 = fma((double)VB.z, wB[2][0], p0);                           \
    p1 = fma((double)VB.z, wB[2][1], p1);                           \
    p2 = fma((double)VB.z, wB[2][2], p2);                           \
    p3 = fma((double)VB.z, wB[2][3], p3);                           \
    p0 = fma((double)VB.w, wB[3][0], p0);                           \
    p1 = fma((double)VB.w, wB[3][1], p1);                           \
    p2 = fma((double)VB.w, wB[3][2], p2);                           \
    p3 = fma((double)VB.w, wB[3][3], p3);                           \
    p0 += __shfl_xor(p0, 1, 64); p1 += __shfl_xor(p1, 1, 64);       \
    p2 += __shfl_xor(p2, 1, 64); p3 += __shfl_xor(p3, 1, 64);       \
    p0 += __shfl_xor(p0, 2, 64); p1 += __shfl_xor(p1, 2, 64);       \
    p2 += __shfl_xor(p2, 2, 64); p3 += __shfl_xor(p3, 2, 64);       \
    p0 += __shfl_xor(p0, 4, 64); p1 += __shfl_xor(p1, 4, 64);       \
    p2 += __shfl_xor(p2, 4, 64); p3 += __shfl_xor(p3, 4, 64);       \
    if (c8 < 4) {                                                   \
      const double v = (c8 == 0) ? p0 : (c8 == 1) ? p1              \
                     : (c8 == 2) ? p2 : p3;                         \
      proj[(size_t)(t00 + (IT) * 8 + tl) * stride +                 \
           (b0 + bl) * 4 + c8] = v;                                 \
    }                                                               \
  }

  LD(0, va0, vb0)
  LD(1, va1, vb1)
  LD(2, va2, vb2)
  CS(0, va0, vb0)
  LD(3, va0, vb0)
  CS(1, va1, vb1)
  LD(4, va1, vb1)
  CS(2, va2, vb2)
  LD(5, va2, vb2)
  CS(3, va0, vb0)
  LD(6, va0, vb0)
  CS(4, va1, vb1)
  LD(7, va1, vb1)
  CS(5, va2, vb2)
  CS(6, va0, vb0)
  CS(7, va1, vb1)

#undef LD
#undef CS
}

// ============ Phase 2: chunked speculative scan + fused expand (v3) =========
// BYTE-IDENTICAL to R10 (CHUNK=128, 32-step pinned prefetch).
// R12 MEASUREMENT: launched 3x (idempotent: rereads proj, rewrites identical
// out). scan_iso = (dur_total - 80.1us) / 2.
__global__ __launch_bounds__(64, 1)
void lif_scan_fused(const double* __restrict__ proj,  // [T][B*NCH]
                    const float* __restrict__ tda,    // [B,TDAF]
                    const float* __restrict__ Wtda,   // [NCH,TDAF]
                    const float* __restrict__ btda,   // [NCH]
                    float* __restrict__ out,          // [B,T,NCH]
                    int B)
{
  __shared__ unsigned long long mlds[64];

  const int lane = threadIdx.x;
  const int nw   = (B * NCH) >> 6;           // waves per chunk
  const int wv   = blockIdx.x % nw;
  const int ck   = blockIdx.x / nw;
  const int g    = wv * 64 + lane;           // chain = b*4+n
  const int b    = g >> 2, n = g & 3;
  const int b0s  = wv * 16;                  // first b of this wave
  const int stride = B * NCH;
  const int t1 = ck * CHUNK;                 // first output step
  const int s0 = (t1 >= WARM) ? (t1 - WARM) : 0;
  const int t2 = t1 + CHUNK;

  double z = (double)btda[n];
  #pragma unroll
  for (int j = 0; j < TDAF; ++j)
    z += (double)tda[b * TDAF + j] * (double)Wtda[n * TDAF + j];
  const double th = 1.0 + 0.3 / (1.0 + exp(-z));

  // 32-step rolling prefetch: four named groups of 8 (fully static indexing)
  double pb0[8], pb1[8], pb2[8], pb3[8];
  #pragma unroll
  for (int e = 0; e < 8; ++e) {
    pb0[e] = proj[(size_t)(s0 +  0 + e) * stride + g];
    pb1[e] = proj[(size_t)(s0 +  8 + e) * stride + g];
    pb2[e] = proj[(size_t)(s0 + 16 + e) * stride + g];
    pb3[e] = proj[(size_t)(s0 + 24 + e) * stride + g];
  }

  double pre = 0.0;
  bool sflag = true;                 // mem = 0 => pre_next = p (select path)

#define RELOAD(PB, TB)                                              \
  {                                                                 \
    _Pragma("unroll")                                               \
    for (int e = 0; e < 8; ++e)                                     \
      PB[e] = proj[(size_t)((TB) + e) * stride + g];                \
  }

#define COMP8_NM(PB)                                                \
  {                                                                 \
    _Pragma("unroll")                                               \
    for (int e = 0; e < 8; ++e) {                                   \
      const double p  = PB[e];                                      \
      const double ac = fma(LEAK, pre, p);                          \
      pre   = sflag ? p : ac;                                       \
      sflag = (pre >= th);                                          \
    }                                                               \
  }

#define COMP8_M(PB, KB)                                             \
  {                                                                 \
    _Pragma("unroll")                                               \
    for (int e = 0; e < 8; ++e) {                                   \
      const double p  = PB[e];                                      \
      const double ac = fma(LEAK, pre, p);                          \
      pre   = sflag ? p : ac;                                       \
      sflag = (pre >= th);                                          \
      mm |= ((unsigned long long)(sflag ? 1u : 0u)) << ((KB) + e);  \
    }                                                               \
  }

  // ---- warm-up (no mask; reloads provably in-bounds: max tt+7 = t1+31 < T)
  for (int t0 = s0; t0 < t1; t0 += 32) {
    COMP8_NM(pb0) RELOAD(pb0, t0 + 32) __builtin_amdgcn_sched_barrier(0);
    COMP8_NM(pb1) RELOAD(pb1, t0 + 40) __builtin_amdgcn_sched_barrier(0);
    COMP8_NM(pb2) RELOAD(pb2, t0 + 48) __builtin_amdgcn_sched_barrier(0);
    COMP8_NM(pb3) RELOAD(pb3, t0 + 56) __builtin_amdgcn_sched_barrier(0);
  }

  // ---- output super-windows (64 steps = 2 halves of 32) ----
  for (int t0 = t1; t0 < t2; t0 += 64) {
    unsigned long long mm = 0ull;
    // half A: steps t0..t0+31 (bits 0..31); reload -> t0+32..t0+63 (< t2 <= T)
    COMP8_M(pb0,  0) RELOAD(pb0, t0 + 32) __builtin_amdgcn_sched_barrier(0);
    COMP8_M(pb1,  8) RELOAD(pb1, t0 + 40) __builtin_amdgcn_sched_barrier(0);
    COMP8_M(pb2, 16) RELOAD(pb2, t0 + 48) __builtin_amdgcn_sched_barrier(0);
    COMP8_M(pb3, 24) RELOAD(pb3, t0 + 56) __builtin_amdgcn_sched_barrier(0);
    // half B: steps t0+32..t0+63 (bits 32..63); reload -> t0+64.. (clamped)
    {
      int u0 = t0 + 64;      if (u0 > T - 8) u0 = T - 8;   // uniform clamps
      int u1 = t0 + 72;      if (u1 > T - 8) u1 = T - 8;   // tail values unused
      int u2 = t0 + 80;      if (u2 > T - 8) u2 = T - 8;
      int u3 = t0 + 88;      if (u3 > T - 8) u3 = T - 8;
      COMP8_M(pb0, 32) RELOAD(pb0, u0) __builtin_amdgcn_sched_barrier(0);
      COMP8_M(pb1, 40) RELOAD(pb1, u1) __builtin_amdgcn_sched_barrier(0);
      COMP8_M(pb2, 48) RELOAD(pb2, u2) __builtin_amdgcn_sched_barrier(0);
      COMP8_M(pb3, 56) RELOAD(pb3, u3) __builtin_amdgcn_sched_barrier(0);
    }
    __syncthreads();                 // reuse of mlds from previous window
    mlds[lane] = mm;
    __syncthreads();
    // expand: lane = t-column; 16 x 1KB-contiguous float4 stores
    #pragma unroll
    for (int bb = 0; bb < 16; ++bb) {
      const unsigned long long m0 = mlds[bb * 4 + 0];
      const unsigned long long m1 = mlds[bb * 4 + 1];
      const unsigned long long m2 = mlds[bb * 4 + 2];
      const unsigned long long m3 = mlds[bb * 4 + 3];
      float4 v;
      v.x = ((m0 >> lane) & 1ull) ? 1.0f : 0.0f;
      v.y = ((m1 >> lane) & 1ull) ? 1.0f : 0.0f;
      v.z = ((m2 >> lane) & 1ull) ? 1.0f : 0.0f;
      v.w = ((m3 >> lane) & 1ull) ? 1.0f : 0.0f;
      float4* o = reinterpret_cast<float4*>(
          out + ((size_t)(b0s + bb) * T + t0 + lane) * NCH);
      *o = v;
    }
  }

#undef RELOAD
#undef COMP8_NM
#undef COMP8_M
}

// ============== Fallback A: R2-verified proj (LDS path, ~86us) =============
__global__ __launch_bounds__(128, 2)
void lif_proj(const float* __restrict__ x, const float* __restrict__ Wsp,
              const float* __restrict__ lat, double* __restrict__ proj, int B)
{
  __shared__ float  xl[32 * 76];
  __shared__ double wl[NCH * C];
  __shared__ double pl[8 * 17];

  const int tid = threadIdx.x;
  const int nb  = B >> 2;
  const int bq  = blockIdx.x % nb;
  const int tq  = blockIdx.x / nb;
  const int b0  = bq << 2;
  const int t00 = tq << 6;
  const int stride = B * NCH;

  #pragma unroll
  for (int k = 0; k < 2; ++k) {
    const int idx = tid + 128 * k;
    const int c = idx >> 2, n = idx & 3;
    double s = 0.0;
    #pragma unroll
    for (int m = 0; m < NCH; ++m)
      s += (double)Wsp[m * C + c] * (double)lat[m * NCH + n];
    wl[n * C + c] = s;
  }
  __syncthreads();

  const int n  = tid & 3;
  const int rr = tid >> 2;
  const int bb = rr >> 3, ii = rr & 7;

  double w[C];
  #pragma unroll
  for (int j = 0; j < C; ++j) w[j] = wl[n * C + j];

  const float4* gx = reinterpret_cast<const float4*>(x);

  for (int ch = 0; ch < 8; ++ch) {
    const int t0 = t00 + (ch << 3);
    __syncthreads();
    #pragma unroll
    for (int k = 0; k < 4; ++k) {
      const int f   = tid + 128 * k;
      const int row = f >> 4, c4 = f & 15;
      const int wb  = row >> 3, wi = row & 7;
      *reinterpret_cast<float4*>(&xl[row * 76 + c4 * 4]) =
          gx[((size_t)(b0 + wb) * T + (t0 + wi)) * 16 + c4];
    }
    __syncthreads();
    const float* rowp = &xl[rr * 76];
    double a0 = 0.0, a1 = 0.0;
    #pragma unroll
    for (int q = 0; q < 16; ++q) {
      const float4 v = *reinterpret_cast<const float4*>(&rowp[4 * q]);
      a0 = fma((double)v.x, w[4 * q + 0], a0);
      a1 = fma((double)v.y, w[4 * q + 1], a1);
      a0 = fma((double)v.z, w[4 * q + 2], a0);
      a1 = fma((double)v.w, w[4 * q + 3], a1);
    }
    pl[ii * 17 + bb * 4 + n] = a0 + a1;
    __syncthreads();
    {
      const int i = tid >> 4, c = tid & 15;
      proj[(size_t)(t0 + i) * stride + b0 * 4 + c] = pl[i * 17 + c];
    }
  }
}

// =================== Fallback B: R2 scan (LDS spike path) ===================
__global__ __launch_bounds__(64)
void lif_scan_lds(const double* __restrict__ proj,
                  const float* __restrict__ tda,
                  const float* __restrict__ Wtda,
                  const float* __restrict__ btda,
                  float* __restrict__ out, int B)
{
  __shared__ float slds[64 * 65];
  const int lane = threadIdx.x;
  const int g = blockIdx.x * 64 + lane;
  const int b = g >> 2, n = g & 3;
  const int b0 = (blockIdx.x * 64) >> 2;
  const int stride = B * NCH;
  double z = (double)btda[n];
  #pragma unroll
  for (int j = 0; j < TDAF; ++j)
    z += (double)tda[b * TDAF + j] * (double)Wtda[n * TDAF + j];
  const double th = 1.0 + 0.3 / (1.0 + exp(-z));
  double pb[8][8];
  #pragma unroll
  for (int j2 = 0; j2 < 8; ++j2)
    #pragma unroll
    for (int e = 0; e < 8; ++e)
      pb[j2][e] = proj[(size_t)(j2 * 8 + e) * stride + g];
  double pre = 0.0;
  bool sflag = true;
  for (int t0 = 0; t0 < T; t0 += 64) {
    #pragma unroll
    for (int j2 = 0; j2 < 8; ++j2) {
      #pragma unroll
      for (int e = 0; e < 8; ++e) {
        const double p  = pb[j2][e];
        const double ac = fma(LEAK, pre, p);
        pre   = sflag ? p : ac;
        sflag = (pre >= th);
        slds[(j2 * 8 + e) * 65 + lane] = sflag ? 1.0f : 0.0f;
      }
      int tt = t0 + 64 + j2 * 8;
      tt = (tt < T) ? tt : (T - 64);
      #pragma unroll
      for (int e = 0; e < 8; ++e)
        pb[j2][e] = proj[(size_t)(tt + e) * stride + g];
    }
    __syncthreads();
    #pragma unroll
    for (int bb = 0; bb < 16; ++bb) {
      #pragma unroll
      for (int h = 0; h < 4; ++h) {
        const int flat = lane + 64 * h;
        const int i = flat >> 2, nn = flat & 3;
        out[((size_t)(b0 + bb) * T + (t0 + i)) * NCH + nn] =
            slds[i * 65 + bb * 4 + nn];
      }
    }
    __syncthreads();
  }
}

// =================== Fallback C: R1 fully fused kernel ======================
namespace fb {
constexpr int TT = 128, NT = T / TT, XPAD = 76, THREADS = 512;
}
__global__ __launch_bounds__(fb::THREADS, 2)
void lif_fused(const float* __restrict__ x, const float* __restrict__ tda,
               const float* __restrict__ Wsp, const float* __restrict__ lat,
               const float* __restrict__ Wtda, const float* __restrict__ btda,
               float* __restrict__ out)
{
  using namespace fb;
  __shared__ float  xl[2][TT * XPAD];
  __shared__ double wl[NCH * C];
  __shared__ double projl[TT * NCH];
  __shared__ float  spikel[TT * NCH];
  __shared__ double thl[NCH];
  const int b = blockIdx.x, tid = threadIdx.x;
  const int n = tid & 3, tl = tid >> 2;
  if (tid < NCH) {
    double z = (double)btda[tid];
    for (int j = 0; j < TDAF; ++j)
      z += (double)tda[b * TDAF + j] * (double)Wtda[tid * TDAF + j];
    thl[tid] = 1.0 + 0.3 / (1.0 + exp(-z));
  }
  if (tid < NCH * C) {
    const int c = tid >> 2, nn = tid & 3;
    double s = 0.0;
    for (int m = 0; m < NCH; ++m)
      s += (double)Wsp[m * C + c] * (double)lat[m * NCH + nn];
    wl[nn * C + c] = s;
  }
  __syncthreads();
  double w[C];
  #pragma unroll
  for (int j = 0; j < C; ++j) w[j] = wl[n * C + j];
  const double th = thl[n];
  const float4* gx = reinterpret_cast<const float4*>(x) + (size_t)b * (T * C / 4);
  float4 ra[4], rb[4];
  #pragma unroll
  for (int r = 0; r < 4; ++r) ra[r] = gx[tid + THREADS * r];
  double pre = 0.0;
  bool sflag = true;
  auto stage = [&](int buf, const float4* rr) {
    #pragma unroll
    for (int r = 0; r < 4; ++r) {
      const int f = tid + THREADS * r;
      const int t = f >> 4, c4 = (f & 15) << 2;
      *reinterpret_cast<float4*>(&xl[buf][t * XPAD + c4]) = rr[r];
    }
  };
  auto prefetch = [&](int k, float4* rr) {
    const float4* src = gx + (size_t)k * (TT * C / 4);
    #pragma unroll
    for (int r = 0; r < 4; ++r) rr[r] = src[tid + THREADS * r];
  };
  auto tilework = [&](int buf, int k) {
    __syncthreads();
    const float* row = &xl[buf][tl * XPAD];
    double a0 = 0.0, a1 = 0.0;
    #pragma unroll
    for (int q = 0; q < 16; ++q) {
      const float4 v = *reinterpret_cast<const float4*>(&row[4 * q]);
      a0 = fma((double)v.x, w[4 * q + 0], a0);
      a1 = fma((double)v.y, w[4 * q + 1], a1);
      a0 = fma((double)v.z, w[4 * q + 2], a0);
      a1 = fma((double)v.w, w[4 * q + 3], a1);
    }
    projl[tid] = a0 + a1;
    __syncthreads();
    if (tid < NCH) {
      #pragma unroll 4
      for (int t = 0; t < TT; ++t) {
        const double p  = projl[t * NCH + tid];
        const double ac = fma(LEAK, pre, p);
        pre   = sflag ? p : ac;
        sflag = (pre >= th);
        spikel[t * NCH + tid] = sflag ? 1.0f : 0.0f;
      }
    }
    __syncthreads();
    out[((size_t)b * T + (size_t)k * TT) * NCH + tid] = spikel[tid];
  };
  for (int k = 0; k < NT; k += 2) {
    stage(0, ra);
    if (k + 1 < NT) prefetch(k + 1, rb);
    tilework(0, k);
    stage(1, rb);
    if (k + 2 < NT) prefetch(k + 2, ra);
    tilework(1, k + 1);
  }
}

extern "C" void kernel_launch(void* const* d_in, const int* in_sizes, int n_in,
                              void* d_out, int out_size, void* d_ws, size_t ws_size,
                              hipStream_t stream) {
  const float* x    = (const float*)d_in[0];
  const float* tda  = (const float*)d_in[1];
  const float* Wsp  = (const float*)d_in[2];
  const float* lat  = (const float*)d_in[3];
  const float* Wtda = (const float*)d_in[4];
  const float* btda = (const float*)d_in[5];
  float* out = (float*)d_out;
  const int B = in_sizes[0] / (T * C);

  const size_t need_proj = (size_t)T * (size_t)B * NCH * sizeof(double);

  if (ws_size >= need_proj && (B % 4) == 0 && (B * NCH) % 64 == 0) {
    double* proj = (double*)d_ws;
    lif_proj3<<<(B / 4) * (T / 64), 256, 0, stream>>>(x, Wsp, lat, proj, B);
    const int grid2 = (T / CHUNK) * ((B * NCH) / 64);
    // MEASUREMENT: scan launched 3x (idempotent; identical out each time).
    // scan_iso = (dur_total - 80.1us) / 2.
    lif_scan_fused<<<grid2, 64, 0, stream>>>(proj, tda, Wtda, btda, out, B);
    lif_scan_fused<<<grid2, 64, 0, stream>>>(proj, tda, Wtda, btda, out, B);
    lif_scan_fused<<<grid2, 64, 0, stream>>>(proj, tda, Wtda, btda, out, B);
  } else if (ws_size >= need_proj && (B % 4) == 0) {
    double* proj = (double*)d_ws;
    lif_proj<<<(B / 4) * (T / 64), 128, 0, stream>>>(x, Wsp, lat, proj, B);
    lif_scan_lds<<<(B * NCH) / 64, 64, 0, stream>>>(proj, tda, Wtda, btda,
                                                    out, B);
  } else {
    lif_fused<<<B, fb::THREADS, 0, stream>>>(x, tda, Wsp, lat, Wtda, btda, out);
  }
}

// Round 13
// 78.910 us; speedup vs baseline: 1.5039x; 1.5039x over previous
//
#include <hip/hip_runtime.h>
#include <math.h>

namespace {
constexpr int T    = 4096;
constexpr int C    = 64;
constexpr int NCH  = 4;
constexpr int TDAF = 50;
constexpr double LEAK = 0.9;
constexpr int CHUNK = 64;    // R13: 128 -> 64 (chain = WARM+CHUNK steps @ ~90cyc)
constexpr int WARM  = 256;   // R13: 384 -> 256 (0.9^256 ~ 2.1e-12; flip prob ~3e-6)
}

// ============================ Phase 1: proj (v4) ===========================
// R7/R8-verified; cold ~57us = ~5.1TB/s read-dominated (near practical BW).
// Depth-3 load pipeline; 256 thr = 32 rows x 8 lanes. grid = (B/4)*(T/64).
// UNCHANGED.
__global__ __launch_bounds__(256, 2)
void lif_proj3(const float* __restrict__ x,    // [B,T,C]
               const float* __restrict__ Wsp,  // [NCH,C]
               const float* __restrict__ lat,  // [NCH,NCH]
               double* __restrict__ proj,      // [T][B*NCH] f64
               int B)
{
  const int tid = threadIdx.x;
  const int nb  = B >> 2;
  const int b0  = (blockIdx.x % nb) << 2;   // 4 b's
  const int t00 = (blockIdx.x / nb) << 6;   // 64 t's
  const int stride = B * NCH;

  const int c8 = tid & 7;                   // column octet 0..7
  const int rr = tid >> 3;                  // 0..31
  const int bl = rr & 3;                    // b_local
  const int tl = rr >> 2;                   // 0..7

  double wA[4][4], wB[4][4];                // [j][n], fully static
  #pragma unroll
  for (int j = 0; j < 4; ++j) {
    const int cA = c8 * 4 + j, cB = 32 + c8 * 4 + j;
    #pragma unroll
    for (int n = 0; n < 4; ++n) {
      double sA = 0.0, sB = 0.0;
      #pragma unroll
      for (int m = 0; m < 4; ++m) {
        sA += (double)Wsp[m * C + cA] * (double)lat[m * NCH + n];
        sB += (double)Wsp[m * C + cB] * (double)lat[m * NCH + n];
      }
      wA[j][n] = sA;
      wB[j][n] = sB;
    }
  }

  const float4* gx = reinterpret_cast<const float4*>(x);
  const size_t rowbase = (size_t)(b0 + bl) * T;

  float4 va0, vb0, va1, vb1, va2, vb2;      // named triple-buffer regs

#define LD(IT, VA, VB)                                              \
  {                                                                 \
    const size_t r16 = (rowbase + (size_t)(t00 + (IT) * 8 + tl)) * 16; \
    VA = gx[r16 + c8];                                              \
    VB = gx[r16 + 8 + c8];                                          \
  }

#define CS(IT, VA, VB)                                              \
  {                                                                 \
    double p0 = 0.0, p1 = 0.0, p2 = 0.0, p3 = 0.0;                  \
    p0 = fma((double)VA.x, wA[0][0], p0);                           \
    p1 = fma((double)VA.x, wA[0][1], p1);                           \
    p2 = fma((double)VA.x, wA[0][2], p2);                           \
    p3 = fma((double)VA.x, wA[0][3], p3);                           \
    p0 = fma((double)VA.y, wA[1][0], p0);                           \
    p1 = fma((double)VA.y, wA[1][1], p1);                           \
    p2 = fma((double)VA.y, wA[1][2], p2);                           \
    p3 = fma((double)VA.y, wA[1][3], p3);                           \
    p0 = fma((double)VA.z, wA[2][0], p0);                           \
    p1 = fma((double)VA.z, wA[2][1], p1);                           \
    p2 = fma((double)VA.z, wA[2][2], p2);                           \
    p3 = fma((double)VA.z, wA[2][3], p3);                           \
    p0 = fma((double)VA.w, wA[3][0], p0);                           \
    p1 = fma((double)VA.w, wA[3][1], p1);                           \
    p2 = fma((double)VA.w, wA[3][2], p2);                           \
    p3 = fma((double)VA.w, wA[3][3], p3);                           \
    p0 = fma((double)VB.x, wB[0][0], p0);                           \
    p1 = fma((double)VB.x, wB[0][1], p1);                           \
    p2 = fma((double)VB.x, wB[0][2], p2);                           \
    p3 = fma((double)VB.x, wB[0][3], p3);                           \
    p0 = fma((double)VB.y, wB[1][0], p0);                           \
    p1 = fma((double)VB.y, wB[1][1], p1);                           \
    p2 = fma((double)VB.y, wB[1][2], p2);                           \
    p3 = fma((double)VB.y, wB[1][3], p3);                           \
    p0 = fma((double)VB.z, wB[2][0], p0);                           \
    p1 = fma((double)VB.z, wB[2][1], p1);                           \
    p2 = fma((double)VB.z, wB[2][2], p2);                           \
    p3 = fma((double)VB.z, wB[2][3], p3);                           \
    p0 = fma((double)VB.w, wB[3][0], p0);                           \
    p1 = fma((double)VB.w, wB[3][1], p1);                           \
    p2 = fma((double)VB.w, wB[3][2], p2);                           \
    p3 = fma((double)VB.w, wB[3][3], p3);                           \
    p0 += __shfl_xor(p0, 1, 64); p1 += __shfl_xor(p1, 1, 64);       \
    p2 += __shfl_xor(p2, 1, 64); p3 += __shfl_xor(p3, 1, 64);       \
    p0 += __shfl_xor(p0, 2, 64); p1 += __shfl_xor(p1, 2, 64);       \
    p2 += __shfl_xor(p2, 2, 64); p3 += __shfl_xor(p3, 2, 64);       \
    p0 += __shfl_xor(p0, 4, 64); p1 += __shfl_xor(p1, 4, 64);       \
    p2 += __shfl_xor(p2, 4, 64); p3 += __shfl_xor(p3, 4, 64);       \
    if (c8 < 4) {                                                   \
      const double v = (c8 == 0) ? p0 : (c8 == 1) ? p1              \
                     : (c8 == 2) ? p2 : p3;                         \
      proj[(size_t)(t00 + (IT) * 8 + tl) * stride +                 \
           (b0 + bl) * 4 + c8] = v;                                 \
    }                                                               \
  }

  LD(0, va0, vb0)
  LD(1, va1, vb1)
  LD(2, va2, vb2)
  CS(0, va0, vb0)
  LD(3, va0, vb0)
  CS(1, va1, vb1)
  LD(4, va1, vb1)
  CS(2, va2, vb2)
  LD(5, va2, vb2)
  CS(3, va0, vb0)
  LD(6, va0, vb0)
  CS(4, va1, vb1)
  LD(7, va1, vb1)
  CS(5, va2, vb2)
  CS(6, va0, vb0)
  CS(7, va1, vb1)

#undef LD
#undef CS
}

// ============ Phase 2: chunked speculative scan + fused expand (v4) =========
// R10-verified structure; R13 = shorter chain (WARM=256, CHUNK=64 -> 320
// serial steps/block @ ~90cyc/step measured R12). grid = (T/CHUNK) *
// (B*NCH/64) = 1024 one-wave blocks (4/CU). Math byte-identical.
__global__ __launch_bounds__(64, 1)
void lif_scan_fused(const double* __restrict__ proj,  // [T][B*NCH]
                    const float* __restrict__ tda,    // [B,TDAF]
                    const float* __restrict__ Wtda,   // [NCH,TDAF]
                    const float* __restrict__ btda,   // [NCH]
                    float* __restrict__ out,          // [B,T,NCH]
                    int B)
{
  __shared__ unsigned long long mlds[64];

  const int lane = threadIdx.x;
  const int nw   = (B * NCH) >> 6;           // waves per chunk
  const int wv   = blockIdx.x % nw;
  const int ck   = blockIdx.x / nw;
  const int g    = wv * 64 + lane;           // chain = b*4+n
  const int b    = g >> 2, n = g & 3;
  const int b0s  = wv * 16;                  // first b of this wave
  const int stride = B * NCH;
  const int t1 = ck * CHUNK;                 // first output step
  const int s0 = (t1 >= WARM) ? (t1 - WARM) : 0;
  const int t2 = t1 + CHUNK;

  double z = (double)btda[n];
  #pragma unroll
  for (int j = 0; j < TDAF; ++j)
    z += (double)tda[b * TDAF + j] * (double)Wtda[n * TDAF + j];
  const double th = 1.0 + 0.3 / (1.0 + exp(-z));

  // 32-step rolling prefetch: four named groups of 8 (fully static indexing)
  double pb0[8], pb1[8], pb2[8], pb3[8];
  #pragma unroll
  for (int e = 0; e < 8; ++e) {
    pb0[e] = proj[(size_t)(s0 +  0 + e) * stride + g];
    pb1[e] = proj[(size_t)(s0 +  8 + e) * stride + g];
    pb2[e] = proj[(size_t)(s0 + 16 + e) * stride + g];
    pb3[e] = proj[(size_t)(s0 + 24 + e) * stride + g];
  }

  double pre = 0.0;
  bool sflag = true;                 // mem = 0 => pre_next = p (select path)

#define RELOAD(PB, TB)                                              \
  {                                                                 \
    _Pragma("unroll")                                               \
    for (int e = 0; e < 8; ++e)                                     \
      PB[e] = proj[(size_t)((TB) + e) * stride + g];                \
  }

#define COMP8_NM(PB)                                                \
  {                                                                 \
    _Pragma("unroll")                                               \
    for (int e = 0; e < 8; ++e) {                                   \
      const double p  = PB[e];                                      \
      const double ac = fma(LEAK, pre, p);                          \
      pre   = sflag ? p : ac;                                       \
      sflag = (pre >= th);                                          \
    }                                                               \
  }

#define COMP8_M(PB, KB)                                             \
  {                                                                 \
    _Pragma("unroll")                                               \
    for (int e = 0; e < 8; ++e) {                                   \
      const double p  = PB[e];                                      \
      const double ac = fma(LEAK, pre, p);                          \
      pre   = sflag ? p : ac;                                       \
      sflag = (pre >= th);                                          \
      mm |= ((unsigned long long)(sflag ? 1u : 0u)) << ((KB) + e);  \
    }                                                               \
  }

  // ---- warm-up (no mask; reloads provably in-bounds: max tt+7 = t1+31 < T)
  for (int t0 = s0; t0 < t1; t0 += 32) {
    COMP8_NM(pb0) RELOAD(pb0, t0 + 32) __builtin_amdgcn_sched_barrier(0);
    COMP8_NM(pb1) RELOAD(pb1, t0 + 40) __builtin_amdgcn_sched_barrier(0);
    COMP8_NM(pb2) RELOAD(pb2, t0 + 48) __builtin_amdgcn_sched_barrier(0);
    COMP8_NM(pb3) RELOAD(pb3, t0 + 56) __builtin_amdgcn_sched_barrier(0);
  }

  // ---- output super-windows (64 steps = 2 halves of 32) ----
  for (int t0 = t1; t0 < t2; t0 += 64) {
    unsigned long long mm = 0ull;
    // half A: steps t0..t0+31 (bits 0..31); reload -> t0+32..t0+63 (< t2 <= T)
    COMP8_M(pb0,  0) RELOAD(pb0, t0 + 32) __builtin_amdgcn_sched_barrier(0);
    COMP8_M(pb1,  8) RELOAD(pb1, t0 + 40) __builtin_amdgcn_sched_barrier(0);
    COMP8_M(pb2, 16) RELOAD(pb2, t0 + 48) __builtin_amdgcn_sched_barrier(0);
    COMP8_M(pb3, 24) RELOAD(pb3, t0 + 56) __builtin_amdgcn_sched_barrier(0);
    // half B: steps t0+32..t0+63 (bits 32..63); reload -> t0+64.. (clamped)
    {
      int u0 = t0 + 64;      if (u0 > T - 8) u0 = T - 8;   // uniform clamps
      int u1 = t0 + 72;      if (u1 > T - 8) u1 = T - 8;   // tail values unused
      int u2 = t0 + 80;      if (u2 > T - 8) u2 = T - 8;
      int u3 = t0 + 88;      if (u3 > T - 8) u3 = T - 8;
      COMP8_M(pb0, 32) RELOAD(pb0, u0) __builtin_amdgcn_sched_barrier(0);
      COMP8_M(pb1, 40) RELOAD(pb1, u1) __builtin_amdgcn_sched_barrier(0);
      COMP8_M(pb2, 48) RELOAD(pb2, u2) __builtin_amdgcn_sched_barrier(0);
      COMP8_M(pb3, 56) RELOAD(pb3, u3) __builtin_amdgcn_sched_barrier(0);
    }
    __syncthreads();                 // reuse of mlds from previous window
    mlds[lane] = mm;
    __syncthreads();
    // expand: lane = t-column; 16 x 1KB-contiguous float4 stores
    #pragma unroll
    for (int bb = 0; bb < 16; ++bb) {
      const unsigned long long m0 = mlds[bb * 4 + 0];
      const unsigned long long m1 = mlds[bb * 4 + 1];
      const unsigned long long m2 = mlds[bb * 4 + 2];
      const unsigned long long m3 = mlds[bb * 4 + 3];
      float4 v;
      v.x = ((m0 >> lane) & 1ull) ? 1.0f : 0.0f;
      v.y = ((m1 >> lane) & 1ull) ? 1.0f : 0.0f;
      v.z = ((m2 >> lane) & 1ull) ? 1.0f : 0.0f;
      v.w = ((m3 >> lane) & 1ull) ? 1.0f : 0.0f;
      float4* o = reinterpret_cast<float4*>(
          out + ((size_t)(b0s + bb) * T + t0 + lane) * NCH);
      *o = v;
    }
  }

#undef RELOAD
#undef COMP8_NM
#undef COMP8_M
}

// ============== Fallback A: R2-verified proj (LDS path, ~86us) =============
__global__ __launch_bounds__(128, 2)
void lif_proj(const float* __restrict__ x, const float* __restrict__ Wsp,
              const float* __restrict__ lat, double* __restrict__ proj, int B)
{
  __shared__ float  xl[32 * 76];
  __shared__ double wl[NCH * C];
  __shared__ double pl[8 * 17];

  const int tid = threadIdx.x;
  const int nb  = B >> 2;
  const int bq  = blockIdx.x % nb;
  const int tq  = blockIdx.x / nb;
  const int b0  = bq << 2;
  const int t00 = tq << 6;
  const int stride = B * NCH;

  #pragma unroll
  for (int k = 0; k < 2; ++k) {
    const int idx = tid + 128 * k;
    const int c = idx >> 2, n = idx & 3;
    double s = 0.0;
    #pragma unroll
    for (int m = 0; m < NCH; ++m)
      s += (double)Wsp[m * C + c] * (double)lat[m * NCH + n];
    wl[n * C + c] = s;
  }
  __syncthreads();

  const int n  = tid & 3;
  const int rr = tid >> 2;
  const int bb = rr >> 3, ii = rr & 7;

  double w[C];
  #pragma unroll
  for (int j = 0; j < C; ++j) w[j] = wl[n * C + j];

  const float4* gx = reinterpret_cast<const float4*>(x);

  for (int ch = 0; ch < 8; ++ch) {
    const int t0 = t00 + (ch << 3);
    __syncthreads();
    #pragma unroll
    for (int k = 0; k < 4; ++k) {
      const int f   = tid + 128 * k;
      const int row = f >> 4, c4 = f & 15;
      const int wb  = row >> 3, wi = row & 7;
      *reinterpret_cast<float4*>(&xl[row * 76 + c4 * 4]) =
          gx[((size_t)(b0 + wb) * T + (t0 + wi)) * 16 + c4];
    }
    __syncthreads();
    const float* rowp = &xl[rr * 76];
    double a0 = 0.0, a1 = 0.0;
    #pragma unroll
    for (int q = 0; q < 16; ++q) {
      const float4 v = *reinterpret_cast<const float4*>(&rowp[4 * q]);
      a0 = fma((double)v.x, w[4 * q + 0], a0);
      a1 = fma((double)v.y, w[4 * q + 1], a1);
      a0 = fma((double)v.z, w[4 * q + 2], a0);
      a1 = fma((double)v.w, w[4 * q + 3], a1);
    }
    pl[ii * 17 + bb * 4 + n] = a0 + a1;
    __syncthreads();
    {
      const int i = tid >> 4, c = tid & 15;
      proj[(size_t)(t0 + i) * stride + b0 * 4 + c] = pl[i * 17 + c];
    }
  }
}

// =================== Fallback B: R2 scan (LDS spike path) ===================
__global__ __launch_bounds__(64)
void lif_scan_lds(const double* __restrict__ proj,
                  const float* __restrict__ tda,
                  const float* __restrict__ Wtda,
                  const float* __restrict__ btda,
                  float* __restrict__ out, int B)
{
  __shared__ float slds[64 * 65];
  const int lane = threadIdx.x;
  const int g = blockIdx.x * 64 + lane;
  const int b = g >> 2, n = g & 3;
  const int b0 = (blockIdx.x * 64) >> 2;
  const int stride = B * NCH;
  double z = (double)btda[n];
  #pragma unroll
  for (int j = 0; j < TDAF; ++j)
    z += (double)tda[b * TDAF + j] * (double)Wtda[n * TDAF + j];
  const double th = 1.0 + 0.3 / (1.0 + exp(-z));
  double pb[8][8];
  #pragma unroll
  for (int j2 = 0; j2 < 8; ++j2)
    #pragma unroll
    for (int e = 0; e < 8; ++e)
      pb[j2][e] = proj[(size_t)(j2 * 8 + e) * stride + g];
  double pre = 0.0;
  bool sflag = true;
  for (int t0 = 0; t0 < T; t0 += 64) {
    #pragma unroll
    for (int j2 = 0; j2 < 8; ++j2) {
      #pragma unroll
      for (int e = 0; e < 8; ++e) {
        const double p  = pb[j2][e];
        const double ac = fma(LEAK, pre, p);
        pre   = sflag ? p : ac;
        sflag = (pre >= th);
        slds[(j2 * 8 + e) * 65 + lane] = sflag ? 1.0f : 0.0f;
      }
      int tt = t0 + 64 + j2 * 8;
      tt = (tt < T) ? tt : (T - 64);
      #pragma unroll
      for (int e = 0; e < 8; ++e)
        pb[j2][e] = proj[(size_t)(tt + e) * stride + g];
    }
    __syncthreads();
    #pragma unroll
    for (int bb = 0; bb < 16; ++bb) {
      #pragma unroll
      for (int h = 0; h < 4; ++h) {
        const int flat = lane + 64 * h;
        const int i = flat >> 2, nn = flat & 3;
        out[((size_t)(b0 + bb) * T + (t0 + i)) * NCH + nn] =
            slds[i * 65 + bb * 4 + nn];
      }
    }
    __syncthreads();
  }
}

// =================== Fallback C: R1 fully fused kernel ======================
namespace fb {
constexpr int TT = 128, NT = T / TT, XPAD = 76, THREADS = 512;
}
__global__ __launch_bounds__(fb::THREADS, 2)
void lif_fused(const float* __restrict__ x, const float* __restrict__ tda,
               const float* __restrict__ Wsp, const float* __restrict__ lat,
               const float* __restrict__ Wtda, const float* __restrict__ btda,
               float* __restrict__ out)
{
  using namespace fb;
  __shared__ float  xl[2][TT * XPAD];
  __shared__ double wl[NCH * C];
  __shared__ double projl[TT * NCH];
  __shared__ float  spikel[TT * NCH];
  __shared__ double thl[NCH];
  const int b = blockIdx.x, tid = threadIdx.x;
  const int n = tid & 3, tl = tid >> 2;
  if (tid < NCH) {
    double z = (double)btda[tid];
    for (int j = 0; j < TDAF; ++j)
      z += (double)tda[b * TDAF + j] * (double)Wtda[tid * TDAF + j];
    thl[tid] = 1.0 + 0.3 / (1.0 + exp(-z));
  }
  if (tid < NCH * C) {
    const int c = tid >> 2, nn = tid & 3;
    double s = 0.0;
    for (int m = 0; m < NCH; ++m)
      s += (double)Wsp[m * C + c] * (double)lat[m * NCH + nn];
    wl[nn * C + c] = s;
  }
  __syncthreads();
  double w[C];
  #pragma unroll
  for (int j = 0; j < C; ++j) w[j] = wl[n * C + j];
  const double th = thl[n];
  const float4* gx = reinterpret_cast<const float4*>(x) + (size_t)b * (T * C / 4);
  float4 ra[4], rb[4];
  #pragma unroll
  for (int r = 0; r < 4; ++r) ra[r] = gx[tid + THREADS * r];
  double pre = 0.0;
  bool sflag = true;
  auto stage = [&](int buf, const float4* rr) {
    #pragma unroll
    for (int r = 0; r < 4; ++r) {
      const int f = tid + THREADS * r;
      const int t = f >> 4, c4 = (f & 15) << 2;
      *reinterpret_cast<float4*>(&xl[buf][t * XPAD + c4]) = rr[r];
    }
  };
  auto prefetch = [&](int k, float4* rr) {
    const float4* src = gx + (size_t)k * (TT * C / 4);
    #pragma unroll
    for (int r = 0; r < 4; ++r) rr[r] = src[tid + THREADS * r];
  };
  auto tilework = [&](int buf, int k) {
    __syncthreads();
    const float* row = &xl[buf][tl * XPAD];
    double a0 = 0.0, a1 = 0.0;
    #pragma unroll
    for (int q = 0; q < 16; ++q) {
      const float4 v = *reinterpret_cast<const float4*>(&row[4 * q]);
      a0 = fma((double)v.x, w[4 * q + 0], a0);
      a1 = fma((double)v.y, w[4 * q + 1], a1);
      a0 = fma((double)v.z, w[4 * q + 2], a0);
      a1 = fma((double)v.w, w[4 * q + 3], a1);
    }
    projl[tid] = a0 + a1;
    __syncthreads();
    if (tid < NCH) {
      #pragma unroll 4
      for (int t = 0; t < TT; ++t) {
        const double p  = projl[t * NCH + tid];
        const double ac = fma(LEAK, pre, p);
        pre   = sflag ? p : ac;
        sflag = (pre >= th);
        spikel[t * NCH + tid] = sflag ? 1.0f : 0.0f;
      }
    }
    __syncthreads();
    out[((size_t)b * T + (size_t)k * TT) * NCH + tid] = spikel[tid];
  };
  for (int k = 0; k < NT; k += 2) {
    stage(0, ra);
    if (k + 1 < NT) prefetch(k + 1, rb);
    tilework(0, k);
    stage(1, rb);
    if (k + 2 < NT) prefetch(k + 2, ra);
    tilework(1, k + 1);
  }
}

extern "C" void kernel_launch(void* const* d_in, const int* in_sizes, int n_in,
                              void* d_out, int out_size, void* d_ws, size_t ws_size,
                              hipStream_t stream) {
  const float* x    = (const float*)d_in[0];
  const float* tda  = (const float*)d_in[1];
  const float* Wsp  = (const float*)d_in[2];
  const float* lat  = (const float*)d_in[3];
  const float* Wtda = (const float*)d_in[4];
  const float* btda = (const float*)d_in[5];
  float* out = (float*)d_out;
  const int B = in_sizes[0] / (T * C);

  const size_t need_proj = (size_t)T * (size_t)B * NCH * sizeof(double);

  if (ws_size >= need_proj && (B % 4) == 0 && (B * NCH) % 64 == 0) {
    double* proj = (double*)d_ws;
    lif_proj3<<<(B / 4) * (T / 64), 256, 0, stream>>>(x, Wsp, lat, proj, B);
    const int grid2 = (T / CHUNK) * ((B * NCH) / 64);
    lif_scan_fused<<<grid2, 64, 0, stream>>>(proj, tda, Wtda, btda, out, B);
  } else if (ws_size >= need_proj && (B % 4) == 0) {
    double* proj = (double*)d_ws;
    lif_proj<<<(B / 4) * (T / 64), 128, 0, stream>>>(x, Wsp, lat, proj, B);
    lif_scan_lds<<<(B * NCH) / 64, 64, 0, stream>>>(proj, tda, Wtda, btda,
                                                    out, B);
  } else {
    lif_fused<<<B, fb::THREADS, 0, stream>>>(x, tda, Wsp, lat, Wtda, btda, out);
  }
}

// Round 14
// 75.996 us; speedup vs baseline: 1.5615x; 1.0383x over previous
//
#include <hip/hip_runtime.h>
#include <math.h>

namespace {
constexpr int T    = 4096;
constexpr int C    = 64;
constexpr int NCH  = 4;
constexpr int TDAF = 50;
constexpr double LEAK = 0.9;
constexpr int CHUNK = 128;   // R14: 64 -> 128. Balances scan's two terms:
                             // L3 re-read BW (117MB ~ 11.5us) vs chain
                             // latency (384 steps x ~33cyc ~ 12.7us).
constexpr int WARM  = 256;   // verified R13 (0.9^256 ~ 2.1e-12, absmax 0.0)
}

// ============================ Phase 1: proj (v4) ===========================
// R7/R8-verified; cold ~57us = ~5.1TB/s read-dominated. Depth-3 load
// pipeline; 256 thr = 32 rows x 8 lanes. grid = (B/4)*(T/64). UNCHANGED.
__global__ __launch_bounds__(256, 2)
void lif_proj3(const float* __restrict__ x,    // [B,T,C]
               const float* __restrict__ Wsp,  // [NCH,C]
               const float* __restrict__ lat,  // [NCH,NCH]
               double* __restrict__ proj,      // [T][B*NCH] f64
               int B)
{
  const int tid = threadIdx.x;
  const int nb  = B >> 2;
  const int b0  = (blockIdx.x % nb) << 2;   // 4 b's
  const int t00 = (blockIdx.x / nb) << 6;   // 64 t's
  const int stride = B * NCH;

  const int c8 = tid & 7;                   // column octet 0..7
  const int rr = tid >> 3;                  // 0..31
  const int bl = rr & 3;                    // b_local
  const int tl = rr >> 2;                   // 0..7

  double wA[4][4], wB[4][4];                // [j][n], fully static
  #pragma unroll
  for (int j = 0; j < 4; ++j) {
    const int cA = c8 * 4 + j, cB = 32 + c8 * 4 + j;
    #pragma unroll
    for (int n = 0; n < 4; ++n) {
      double sA = 0.0, sB = 0.0;
      #pragma unroll
      for (int m = 0; m < 4; ++m) {
        sA += (double)Wsp[m * C + cA] * (double)lat[m * NCH + n];
        sB += (double)Wsp[m * C + cB] * (double)lat[m * NCH + n];
      }
      wA[j][n] = sA;
      wB[j][n] = sB;
    }
  }

  const float4* gx = reinterpret_cast<const float4*>(x);
  const size_t rowbase = (size_t)(b0 + bl) * T;

  float4 va0, vb0, va1, vb1, va2, vb2;      // named triple-buffer regs

#define LD(IT, VA, VB)                                              \
  {                                                                 \
    const size_t r16 = (rowbase + (size_t)(t00 + (IT) * 8 + tl)) * 16; \
    VA = gx[r16 + c8];                                              \
    VB = gx[r16 + 8 + c8];                                          \
  }

#define CS(IT, VA, VB)                                              \
  {                                                                 \
    double p0 = 0.0, p1 = 0.0, p2 = 0.0, p3 = 0.0;                  \
    p0 = fma((double)VA.x, wA[0][0], p0);                           \
    p1 = fma((double)VA.x, wA[0][1], p1);                           \
    p2 = fma((double)VA.x, wA[0][2], p2);                           \
    p3 = fma((double)VA.x, wA[0][3], p3);                           \
    p0 = fma((double)VA.y, wA[1][0], p0);                           \
    p1 = fma((double)VA.y, wA[1][1], p1);                           \
    p2 = fma((double)VA.y, wA[1][2], p2);                           \
    p3 = fma((double)VA.y, wA[1][3], p3);                           \
    p0 = fma((double)VA.z, wA[2][0], p0);                           \
    p1 = fma((double)VA.z, wA[2][1], p1);                           \
    p2 = fma((double)VA.z, wA[2][2], p2);                           \
    p3 = fma((double)VA.z, wA[2][3], p3);                           \
    p0 = fma((double)VA.w, wA[3][0], p0);                           \
    p1 = fma((double)VA.w, wA[3][1], p1);                           \
    p2 = fma((double)VA.w, wA[3][2], p2);                           \
    p3 = fma((double)VA.w, wA[3][3], p3);                           \
    p0 = fma((double)VB.x, wB[0][0], p0);                           \
    p1 = fma((double)VB.x, wB[0][1], p1);                           \
    p2 = fma((double)VB.x, wB[0][2], p2);                           \
    p3 = fma((double)VB.x, wB[0][3], p3);                           \
    p0 = fma((double)VB.y, wB[1][0], p0);                           \
    p1 = fma((double)VB.y, wB[1][1], p1);                           \
    p2 = fma((double)VB.y, wB[1][2], p2);                           \
    p3 = fma((double)VB.y, wB[1][3], p3);                           \
    p0 = fma((double)VB.z, wB[2][0], p0);                           \
    p1 = fma((double)VB.z, wB[2][1], p1);                           \
    p2 = fma((double)VB.z, wB[2][2], p2);                           \
    p3 = fma((double)VB.z, wB[2][3], p3);                           \
    p0 = fma((double)VB.w, wB[3][0], p0);                           \
    p1 = fma((double)VB.w, wB[3][1], p1);                           \
    p2 = fma((double)VB.w, wB[3][2], p2);                           \
    p3 = fma((double)VB.w, wB[3][3], p3);                           \
    p0 += __shfl_xor(p0, 1, 64); p1 += __shfl_xor(p1, 1, 64);       \
    p2 += __shfl_xor(p2, 1, 64); p3 += __shfl_xor(p3, 1, 64);       \
    p0 += __shfl_xor(p0, 2, 64); p1 += __shfl_xor(p1, 2, 64);       \
    p2 += __shfl_xor(p2, 2, 64); p3 += __shfl_xor(p3, 2, 64);       \
    p0 += __shfl_xor(p0, 4, 64); p1 += __shfl_xor(p1, 4, 64);       \
    p2 += __shfl_xor(p2, 4, 64); p3 += __shfl_xor(p3, 4, 64);       \
    if (c8 < 4) {                                                   \
      const double v = (c8 == 0) ? p0 : (c8 == 1) ? p1              \
                     : (c8 == 2) ? p2 : p3;                         \
      proj[(size_t)(t00 + (IT) * 8 + tl) * stride +                 \
           (b0 + bl) * 4 + c8] = v;                                 \
    }                                                               \
  }

  LD(0, va0, vb0)
  LD(1, va1, vb1)
  LD(2, va2, vb2)
  CS(0, va0, vb0)
  LD(3, va0, vb0)
  CS(1, va1, vb1)
  LD(4, va1, vb1)
  CS(2, va2, vb2)
  LD(5, va2, vb2)
  CS(3, va0, vb0)
  LD(6, va0, vb0)
  CS(4, va1, vb1)
  LD(7, va1, vb1)
  CS(5, va2, vb2)
  CS(6, va0, vb0)
  CS(7, va1, vb1)

#undef LD
#undef CS
}

// ============ Phase 2: chunked speculative scan + fused expand (v4) =========
// R10/R13-verified structure; R14 = CHUNK 64->128 at WARM=256 (joint minimum
// of L3-BW and chain-latency terms). grid = (T/CHUNK) * (B*NCH/64) = 512
// one-wave blocks. Math byte-identical.
__global__ __launch_bounds__(64, 1)
void lif_scan_fused(const double* __restrict__ proj,  // [T][B*NCH]
                    const float* __restrict__ tda,    // [B,TDAF]
                    const float* __restrict__ Wtda,   // [NCH,TDAF]
                    const float* __restrict__ btda,   // [NCH]
                    float* __restrict__ out,          // [B,T,NCH]
                    int B)
{
  __shared__ unsigned long long mlds[64];

  const int lane = threadIdx.x;
  const int nw   = (B * NCH) >> 6;           // waves per chunk
  const int wv   = blockIdx.x % nw;
  const int ck   = blockIdx.x / nw;
  const int g    = wv * 64 + lane;           // chain = b*4+n
  const int b    = g >> 2, n = g & 3;
  const int b0s  = wv * 16;                  // first b of this wave
  const int stride = B * NCH;
  const int t1 = ck * CHUNK;                 // first output step
  const int s0 = (t1 >= WARM) ? (t1 - WARM) : 0;
  const int t2 = t1 + CHUNK;

  double z = (double)btda[n];
  #pragma unroll
  for (int j = 0; j < TDAF; ++j)
    z += (double)tda[b * TDAF + j] * (double)Wtda[n * TDAF + j];
  const double th = 1.0 + 0.3 / (1.0 + exp(-z));

  // 32-step rolling prefetch: four named groups of 8 (fully static indexing)
  double pb0[8], pb1[8], pb2[8], pb3[8];
  #pragma unroll
  for (int e = 0; e < 8; ++e) {
    pb0[e] = proj[(size_t)(s0 +  0 + e) * stride + g];
    pb1[e] = proj[(size_t)(s0 +  8 + e) * stride + g];
    pb2[e] = proj[(size_t)(s0 + 16 + e) * stride + g];
    pb3[e] = proj[(size_t)(s0 + 24 + e) * stride + g];
  }

  double pre = 0.0;
  bool sflag = true;                 // mem = 0 => pre_next = p (select path)

#define RELOAD(PB, TB)                                              \
  {                                                                 \
    _Pragma("unroll")                                               \
    for (int e = 0; e < 8; ++e)                                     \
      PB[e] = proj[(size_t)((TB) + e) * stride + g];                \
  }

#define COMP8_NM(PB)                                                \
  {                                                                 \
    _Pragma("unroll")                                               \
    for (int e = 0; e < 8; ++e) {                                   \
      const double p  = PB[e];                                      \
      const double ac = fma(LEAK, pre, p);                          \
      pre   = sflag ? p : ac;                                       \
      sflag = (pre >= th);                                          \
    }                                                               \
  }

#define COMP8_M(PB, KB)                                             \
  {                                                                 \
    _Pragma("unroll")                                               \
    for (int e = 0; e < 8; ++e) {                                   \
      const double p  = PB[e];                                      \
      const double ac = fma(LEAK, pre, p);                          \
      pre   = sflag ? p : ac;                                       \
      sflag = (pre >= th);                                          \
      mm |= ((unsigned long long)(sflag ? 1u : 0u)) << ((KB) + e);  \
    }                                                               \
  }

  // ---- warm-up (no mask; reloads provably in-bounds: max tt+7 = t1+31 < T)
  for (int t0 = s0; t0 < t1; t0 += 32) {
    COMP8_NM(pb0) RELOAD(pb0, t0 + 32) __builtin_amdgcn_sched_barrier(0);
    COMP8_NM(pb1) RELOAD(pb1, t0 + 40) __builtin_amdgcn_sched_barrier(0);
    COMP8_NM(pb2) RELOAD(pb2, t0 + 48) __builtin_amdgcn_sched_barrier(0);
    COMP8_NM(pb3) RELOAD(pb3, t0 + 56) __builtin_amdgcn_sched_barrier(0);
  }

  // ---- output super-windows (64 steps = 2 halves of 32) ----
  for (int t0 = t1; t0 < t2; t0 += 64) {
    unsigned long long mm = 0ull;
    // half A: steps t0..t0+31 (bits 0..31); reload -> t0+32..t0+63 (< t2 <= T)
    COMP8_M(pb0,  0) RELOAD(pb0, t0 + 32) __builtin_amdgcn_sched_barrier(0);
    COMP8_M(pb1,  8) RELOAD(pb1, t0 + 40) __builtin_amdgcn_sched_barrier(0);
    COMP8_M(pb2, 16) RELOAD(pb2, t0 + 48) __builtin_amdgcn_sched_barrier(0);
    COMP8_M(pb3, 24) RELOAD(pb3, t0 + 56) __builtin_amdgcn_sched_barrier(0);
    // half B: steps t0+32..t0+63 (bits 32..63); reload -> t0+64.. (clamped)
    {
      int u0 = t0 + 64;      if (u0 > T - 8) u0 = T - 8;   // uniform clamps
      int u1 = t0 + 72;      if (u1 > T - 8) u1 = T - 8;   // tail values unused
      int u2 = t0 + 80;      if (u2 > T - 8) u2 = T - 8;
      int u3 = t0 + 88;      if (u3 > T - 8) u3 = T - 8;
      COMP8_M(pb0, 32) RELOAD(pb0, u0) __builtin_amdgcn_sched_barrier(0);
      COMP8_M(pb1, 40) RELOAD(pb1, u1) __builtin_amdgcn_sched_barrier(0);
      COMP8_M(pb2, 48) RELOAD(pb2, u2) __builtin_amdgcn_sched_barrier(0);
      COMP8_M(pb3, 56) RELOAD(pb3, u3) __builtin_amdgcn_sched_barrier(0);
    }
    __syncthreads();                 // reuse of mlds from previous window
    mlds[lane] = mm;
    __syncthreads();
    // expand: lane = t-column; 16 x 1KB-contiguous float4 stores
    #pragma unroll
    for (int bb = 0; bb < 16; ++bb) {
      const unsigned long long m0 = mlds[bb * 4 + 0];
      const unsigned long long m1 = mlds[bb * 4 + 1];
      const unsigned long long m2 = mlds[bb * 4 + 2];
      const unsigned long long m3 = mlds[bb * 4 + 3];
      float4 v;
      v.x = ((m0 >> lane) & 1ull) ? 1.0f : 0.0f;
      v.y = ((m1 >> lane) & 1ull) ? 1.0f : 0.0f;
      v.z = ((m2 >> lane) & 1ull) ? 1.0f : 0.0f;
      v.w = ((m3 >> lane) & 1ull) ? 1.0f : 0.0f;
      float4* o = reinterpret_cast<float4*>(
          out + ((size_t)(b0s + bb) * T + t0 + lane) * NCH);
      *o = v;
    }
  }

#undef RELOAD
#undef COMP8_NM
#undef COMP8_M
}

// ============== Fallback A: R2-verified proj (LDS path, ~86us) =============
__global__ __launch_bounds__(128, 2)
void lif_proj(const float* __restrict__ x, const float* __restrict__ Wsp,
              const float* __restrict__ lat, double* __restrict__ proj, int B)
{
  __shared__ float  xl[32 * 76];
  __shared__ double wl[NCH * C];
  __shared__ double pl[8 * 17];

  const int tid = threadIdx.x;
  const int nb  = B >> 2;
  const int bq  = blockIdx.x % nb;
  const int tq  = blockIdx.x / nb;
  const int b0  = bq << 2;
  const int t00 = tq << 6;
  const int stride = B * NCH;

  #pragma unroll
  for (int k = 0; k < 2; ++k) {
    const int idx = tid + 128 * k;
    const int c = idx >> 2, n = idx & 3;
    double s = 0.0;
    #pragma unroll
    for (int m = 0; m < NCH; ++m)
      s += (double)Wsp[m * C + c] * (double)lat[m * NCH + n];
    wl[n * C + c] = s;
  }
  __syncthreads();

  const int n  = tid & 3;
  const int rr = tid >> 2;
  const int bb = rr >> 3, ii = rr & 7;

  double w[C];
  #pragma unroll
  for (int j = 0; j < C; ++j) w[j] = wl[n * C + j];

  const float4* gx = reinterpret_cast<const float4*>(x);

  for (int ch = 0; ch < 8; ++ch) {
    const int t0 = t00 + (ch << 3);
    __syncthreads();
    #pragma unroll
    for (int k = 0; k < 4; ++k) {
      const int f   = tid + 128 * k;
      const int row = f >> 4, c4 = f & 15;
      const int wb  = row >> 3, wi = row & 7;
      *reinterpret_cast<float4*>(&xl[row * 76 + c4 * 4]) =
          gx[((size_t)(b0 + wb) * T + (t0 + wi)) * 16 + c4];
    }
    __syncthreads();
    const float* rowp = &xl[rr * 76];
    double a0 = 0.0, a1 = 0.0;
    #pragma unroll
    for (int q = 0; q < 16; ++q) {
      const float4 v = *reinterpret_cast<const float4*>(&rowp[4 * q]);
      a0 = fma((double)v.x, w[4 * q + 0], a0);
      a1 = fma((double)v.y, w[4 * q + 1], a1);
      a0 = fma((double)v.z, w[4 * q + 2], a0);
      a1 = fma((double)v.w, w[4 * q + 3], a1);
    }
    pl[ii * 17 + bb * 4 + n] = a0 + a1;
    __syncthreads();
    {
      const int i = tid >> 4, c = tid & 15;
      proj[(size_t)(t0 + i) * stride + b0 * 4 + c] = pl[i * 17 + c];
    }
  }
}

// =================== Fallback B: R2 scan (LDS spike path) ===================
__global__ __launch_bounds__(64)
void lif_scan_lds(const double* __restrict__ proj,
                  const float* __restrict__ tda,
                  const float* __restrict__ Wtda,
                  const float* __restrict__ btda,
                  float* __restrict__ out, int B)
{
  __shared__ float slds[64 * 65];
  const int lane = threadIdx.x;
  const int g = blockIdx.x * 64 + lane;
  const int b = g >> 2, n = g & 3;
  const int b0 = (blockIdx.x * 64) >> 2;
  const int stride = B * NCH;
  double z = (double)btda[n];
  #pragma unroll
  for (int j = 0; j < TDAF; ++j)
    z += (double)tda[b * TDAF + j] * (double)Wtda[n * TDAF + j];
  const double th = 1.0 + 0.3 / (1.0 + exp(-z));
  double pb[8][8];
  #pragma unroll
  for (int j2 = 0; j2 < 8; ++j2)
    #pragma unroll
    for (int e = 0; e < 8; ++e)
      pb[j2][e] = proj[(size_t)(j2 * 8 + e) * stride + g];
  double pre = 0.0;
  bool sflag = true;
  for (int t0 = 0; t0 < T; t0 += 64) {
    #pragma unroll
    for (int j2 = 0; j2 < 8; ++j2) {
      #pragma unroll
      for (int e = 0; e < 8; ++e) {
        const double p  = pb[j2][e];
        const double ac = fma(LEAK, pre, p);
        pre   = sflag ? p : ac;
        sflag = (pre >= th);
        slds[(j2 * 8 + e) * 65 + lane] = sflag ? 1.0f : 0.0f;
      }
      int tt = t0 + 64 + j2 * 8;
      tt = (tt < T) ? tt : (T - 64);
      #pragma unroll
      for (int e = 0; e < 8; ++e)
        pb[j2][e] = proj[(size_t)(tt + e) * stride + g];
    }
    __syncthreads();
    #pragma unroll
    for (int bb = 0; bb < 16; ++bb) {
      #pragma unroll
      for (int h = 0; h < 4; ++h) {
        const int flat = lane + 64 * h;
        const int i = flat >> 2, nn = flat & 3;
        out[((size_t)(b0 + bb) * T + (t0 + i)) * NCH + nn] =
            slds[i * 65 + bb * 4 + nn];
      }
    }
    __syncthreads();
  }
}

// =================== Fallback C: R1 fully fused kernel ======================
namespace fb {
constexpr int TT = 128, NT = T / TT, XPAD = 76, THREADS = 512;
}
__global__ __launch_bounds__(fb::THREADS, 2)
void lif_fused(const float* __restrict__ x, const float* __restrict__ tda,
               const float* __restrict__ Wsp, const float* __restrict__ lat,
               const float* __restrict__ Wtda, const float* __restrict__ btda,
               float* __restrict__ out)
{
  using namespace fb;
  __shared__ float  xl[2][TT * XPAD];
  __shared__ double wl[NCH * C];
  __shared__ double projl[TT * NCH];
  __shared__ float  spikel[TT * NCH];
  __shared__ double thl[NCH];
  const int b = blockIdx.x, tid = threadIdx.x;
  const int n = tid & 3, tl = tid >> 2;
  if (tid < NCH) {
    double z = (double)btda[tid];
    for (int j = 0; j < TDAF; ++j)
      z += (double)tda[b * TDAF + j] * (double)Wtda[tid * TDAF + j];
    thl[tid] = 1.0 + 0.3 / (1.0 + exp(-z));
  }
  if (tid < NCH * C) {
    const int c = tid >> 2, nn = tid & 3;
    double s = 0.0;
    for (int m = 0; m < NCH; ++m)
      s += (double)Wsp[m * C + c] * (double)lat[m * NCH + nn];
    wl[nn * C + c] = s;
  }
  __syncthreads();
  double w[C];
  #pragma unroll
  for (int j = 0; j < C; ++j) w[j] = wl[n * C + j];
  const double th = thl[n];
  const float4* gx = reinterpret_cast<const float4*>(x) + (size_t)b * (T * C / 4);
  float4 ra[4], rb[4];
  #pragma unroll
  for (int r = 0; r < 4; ++r) ra[r] = gx[tid + THREADS * r];
  double pre = 0.0;
  bool sflag = true;
  auto stage = [&](int buf, const float4* rr) {
    #pragma unroll
    for (int r = 0; r < 4; ++r) {
      const int f = tid + THREADS * r;
      const int t = f >> 4, c4 = (f & 15) << 2;
      *reinterpret_cast<float4*>(&xl[buf][t * XPAD + c4]) = rr[r];
    }
  };
  auto prefetch = [&](int k, float4* rr) {
    const float4* src = gx + (size_t)k * (TT * C / 4);
    #pragma unroll
    for (int r = 0; r < 4; ++r) rr[r] = src[tid + THREADS * r];
  };
  auto tilework = [&](int buf, int k) {
    __syncthreads();
    const float* row = &xl[buf][tl * XPAD];
    double a0 = 0.0, a1 = 0.0;
    #pragma unroll
    for (int q = 0; q < 16; ++q) {
      const float4 v = *reinterpret_cast<const float4*>(&row[4 * q]);
      a0 = fma((double)v.x, w[4 * q + 0], a0);
      a1 = fma((double)v.y, w[4 * q + 1], a1);
      a0 = fma((double)v.z, w[4 * q + 2], a0);
      a1 = fma((double)v.w, w[4 * q + 3], a1);
    }
    projl[tid] = a0 + a1;
    __syncthreads();
    if (tid < NCH) {
      #pragma unroll 4
      for (int t = 0; t < TT; ++t) {
        const double p  = projl[t * NCH + tid];
        const double ac = fma(LEAK, pre, p);
        pre   = sflag ? p : ac;
        sflag = (pre >= th);
        spikel[t * NCH + tid] = sflag ? 1.0f : 0.0f;
      }
    }
    __syncthreads();
    out[((size_t)b * T + (size_t)k * TT) * NCH + tid] = spikel[tid];
  };
  for (int k = 0; k < NT; k += 2) {
    stage(0, ra);
    if (k + 1 < NT) prefetch(k + 1, rb);
    tilework(0, k);
    stage(1, rb);
    if (k + 2 < NT) prefetch(k + 2, ra);
    tilework(1, k + 1);
  }
}

extern "C" void kernel_launch(void* const* d_in, const int* in_sizes, int n_in,
                              void* d_out, int out_size, void* d_ws, size_t ws_size,
                              hipStream_t stream) {
  const float* x    = (const float*)d_in[0];
  const float* tda  = (const float*)d_in[1];
  const float* Wsp  = (const float*)d_in[2];
  const float* lat  = (const float*)d_in[3];
  const float* Wtda = (const float*)d_in[4];
  const float* btda = (const float*)d_in[5];
  float* out = (float*)d_out;
  const int B = in_sizes[0] / (T * C);

  const size_t need_proj = (size_t)T * (size_t)B * NCH * sizeof(double);

  if (ws_size >= need_proj && (B % 4) == 0 && (B * NCH) % 64 == 0) {
    double* proj = (double*)d_ws;
    lif_proj3<<<(B / 4) * (T / 64), 256, 0, stream>>>(x, Wsp, lat, proj, B);
    const int grid2 = (T / CHUNK) * ((B * NCH) / 64);
    lif_scan_fused<<<grid2, 64, 0, stream>>>(proj, tda, Wtda, btda, out, B);
  } else if (ws_size >= need_proj && (B % 4) == 0) {
    double* proj = (double*)d_ws;
    lif_proj<<<(B / 4) * (T / 64), 128, 0, stream>>>(x, Wsp, lat, proj, B);
    lif_scan_lds<<<(B * NCH) / 64, 64, 0, stream>>>(proj, tda, Wtda, btda,
                                                    out, B);
  } else {
    lif_fused<<<B, fb::THREADS, 0, stream>>>(x, tda, Wsp, lat, Wtda, btda, out);
  }
}